// Round 5
// baseline (524.792 us; speedup 1.0000x reference)
//
#include <hip/hip_runtime.h>
#include <hip/hip_bf16.h>

#define ROWS 1025   // B*N + 1
#define DD   128    // D
#define C3   384    // 3*D
#define BB   8
#define NN   128

#define NL2E  (-1.4426950408889634f)   // -log2(e)

__device__ __forceinline__ float bf2f(unsigned short u) {
    return __uint_as_float(((unsigned int)u) << 16);
}
__device__ __forceinline__ unsigned short f2bf(float f) {
    unsigned int i = __float_as_uint(f);            // finite data only
    return (unsigned short)((i + 0x7FFFu + ((i >> 16) & 1u)) >> 16);
}

// Pre-scaled packed gate tables, bf16x4 per (row, d):
//   GiP[row][d] = {-L*ir, -L*iz, -2L*in, 0}
//   GhP[row][d] = {-L*hr, -L*hz, -2L*hn, h}
// so that sigmoid(ir+hr) = rcp(1 + exp2(girs+ghrs)), tanh(in + r*hn) =
// 2*rcp(1 + exp2(gins + r*ghns)) - 1.
// Unit = (row-chunk of 4 rows) x (col-chunk of 256 combined cols out of 768).
__global__ __launch_bounds__(256, 8) void gtab_kernel(
    const float* __restrict__ h,
    const float* __restrict__ Wi, const float* __restrict__ Wh,
    const float* __restrict__ bi, const float* __restrict__ bh,
    unsigned short* __restrict__ GiP, unsigned short* __restrict__ GhP) {
    __shared__ float hs[4][DD];
    const int t = threadIdx.x;
    const int rblk = blockIdx.x / 3, cch = blockIdx.x % 3;
    const int r0 = rblk * 4;
    for (int idx = t; idx < 4 * DD; idx += 256) {
        int r = idx >> 7, k = idx & (DD - 1);
        hs[r][k] = (r0 + r < ROWS) ? h[(size_t)(r0 + r) * DD + k] : 0.0f;
    }
    __syncthreads();
    if (cch == 0 && t < DD) {
#pragma unroll
        for (int r = 0; r < 4; ++r)
            if (r0 + r < ROWS) GhP[(size_t)(r0 + r) * 512 + t * 4 + 3] = f2bf(hs[r][t]);
    }
    const int  c   = cch * 256 + t;      // combined col 0..767
    const bool isI = (c < C3);
    const int  cc  = isI ? c : c - C3;
    const float* __restrict__ w = (isI ? Wi : Wh) + (size_t)cc * DD;
    float acc[4] = {0.f, 0.f, 0.f, 0.f};
    for (int k = 0; k < DD; k += 4) {
        float4 wv = *reinterpret_cast<const float4*>(w + k);
#pragma unroll
        for (int r = 0; r < 4; ++r) {
            acc[r] += hs[r][k] * wv.x + hs[r][k + 1] * wv.y
                    + hs[r][k + 2] * wv.z + hs[r][k + 3] * wv.w;
        }
    }
    const float bv = (isI ? bi : bh)[cc];
    const int s = cc >> 7, d = cc & (DD - 1);
    const float scale = (s == 2) ? 2.0f * NL2E : NL2E;
    unsigned short* __restrict__ G = isI ? GiP : GhP;
#pragma unroll
    for (int r = 0; r < 4; ++r)
        if (r0 + r < ROWS) G[(size_t)(r0 + r) * 512 + d * 4 + s] = f2bf((acc[r] + bv) * scale);
}

// One block per (b,j); 512 threads = (ic 0..3) x (d 0..127); quarter ic sums 32 i's.
// XC=1: x=child, h=parent (bwd). XC=0: x=parent, h=child (fwd).
template<int XC, int WRITE_OUT>
__global__ __launch_bounds__(512, 8) void phase_kernel(
    const float* __restrict__ hin,
    const int* __restrict__ parent, const int* __restrict__ child,
    const unsigned short* __restrict__ GiP, const unsigned short* __restrict__ GhP,
    float* __restrict__ hout,
    const int* __restrict__ tgt, float* __restrict__ out) {
    const int bj = blockIdx.x;          // 0..1023
    const int t  = threadIdx.x;
    const int b  = bj >> 7, j = bj & (NN - 1);
    const size_t base = (size_t)b * NN * NN + j;          // + i*NN

    __shared__ int   pcs[2 * NN];       // interleaved {p,c} pairs
    __shared__ float sacc[4][DD];
    if (t < NN)            pcs[2 * t]            = parent[base + (size_t)t * NN];
    else if (t < 2 * NN)   pcs[2 * (t - NN) + 1] = child [base + (size_t)(t - NN) * NN];
    __syncthreads();

    const int ic = t >> 7, d = t & (DD - 1);
    float acc = 0.0f;
#pragma unroll 4
    for (int k = 0; k < 32; ++k) {
        const int  i  = ic * 32 + k;
        const int2 pc = *reinterpret_cast<const int2*>(&pcs[2 * i]);
        const int  xi = XC ? pc.y : pc.x;
        const int  hi = XC ? pc.x : pc.y;
        const ushort4 vx = *reinterpret_cast<const ushort4*>(GiP + (size_t)xi * 512 + d * 4);
        const ushort4 vh = *reinterpret_cast<const ushort4*>(GhP + (size_t)hi * 512 + d * 4);
        const float irs = bf2f(vx.x), izs = bf2f(vx.y), ins = bf2f(vx.z);
        const float hrs = bf2f(vh.x), hzs = bf2f(vh.y), hns = bf2f(vh.z), hv = bf2f(vh.w);
        const float r = __builtin_amdgcn_rcpf(1.0f + __builtin_amdgcn_exp2f(irs + hrs));
        const float z = __builtin_amdgcn_rcpf(1.0f + __builtin_amdgcn_exp2f(izs + hzs));
        const float q = __builtin_amdgcn_rcpf(1.0f + __builtin_amdgcn_exp2f(ins + r * hns));
        const float n = 2.0f * q - 1.0f;
        acc += n + z * (hv - n);
    }
    sacc[ic][d] = acc;
    __syncthreads();

    if (ic == 0) {
        const float v   = sacc[0][d] + sacc[1][d] + sacc[2][d] + sacc[3][d];
        const int   row = 1 + bj;
        const float res = hin[(size_t)row * DD + d] + v;
        if (WRITE_OUT) {
#pragma unroll
            for (int bb = 0; bb < BB; ++bb)
                if (tgt[bb] == row) out[bb * DD + d] = res;
        } else {
            hout[(size_t)row * DD + d] = res;
        }
    } else if (ic == 1 && bj == 0 && !WRITE_OUT) {
        hout[d] = hin[d];                 // row 0 unchanged (tgt >= 1 always)
    }
}

extern "C" void kernel_launch(void* const* d_in, const int* in_sizes, int n_in,
                              void* d_out, int out_size, void* d_ws, size_t ws_size,
                              hipStream_t stream) {
    const float* hidden = (const float*)d_in[0];
    const int*   parent = (const int*)d_in[1];
    const int*   child  = (const int*)d_in[2];
    const int*   tgt    = (const int*)d_in[3];
    const float* Wif    = (const float*)d_in[4];
    const float* Whf    = (const float*)d_in[5];
    const float* bif    = (const float*)d_in[6];
    const float* bhf    = (const float*)d_in[7];
    const float* Wib    = (const float*)d_in[8];
    const float* Whb    = (const float*)d_in[9];
    const float* bib    = (const float*)d_in[10];
    const float* bhb    = (const float*)d_in[11];

    char* ws = (char*)d_ws;
    unsigned short* GiP = (unsigned short*)(ws);                  // 1025*512 bf16
    unsigned short* GhP = (unsigned short*)(ws + 1049600);        // 1025*512 bf16
    float*          h1  = (float*)(ws + 2099200);                 // 1025*128 f32
    float*          out = (float*)d_out;

    // Phase 1: bwd weights, x = child, h = parent
    gtab_kernel<<<771, 256, 0, stream>>>(hidden, Wib, Whb, bib, bhb, GiP, GhP);
    phase_kernel<1, 0><<<BB * NN, 512, 0, stream>>>(hidden, parent, child, GiP, GhP, h1, nullptr, nullptr);
    // Phase 2: fwd weights, x = parent, h = child; tgt gather fused
    gtab_kernel<<<771, 256, 0, stream>>>(h1, Wif, Whf, bif, bhf, GiP, GhP);
    phase_kernel<0, 1><<<BB * NN, 512, 0, stream>>>(h1, parent, child, GiP, GhP, nullptr, tgt, out);
}

// Round 6
// 76.884 us; speedup vs baseline: 6.8258x; 6.8258x over previous
//
#include <hip/hip_runtime.h>
#include <hip/hip_bf16.h>

#define ROWS 1025   // B*N + 1
#define DD   128    // D
#define C3   384    // 3*D
#define BB   8
#define NN   128

#define NL2E  (-1.4426950408889634f)   // -log2(e)

__device__ __forceinline__ float bf2f(unsigned short u) {
    return __uint_as_float(((unsigned int)u) << 16);
}
__device__ __forceinline__ unsigned short f2bf(float f) {
    unsigned int i = __float_as_uint(f);            // finite data only
    return (unsigned short)((i + 0x7FFFu + ((i >> 16) & 1u)) >> 16);
}

// Transpose + pre-scale the 4 weight matrices [384][128] -> [128][384]:
//   WT[k][cc] = W[cc][k] * (cc>=256 ? 2*NL2E : NL2E)
// 48 tiles (12 x 4 of 32x32) per matrix, 4 matrices = 192 blocks.
__global__ __launch_bounds__(256) void wprep_kernel(
    const float* __restrict__ Wib, const float* __restrict__ Whb,
    const float* __restrict__ Wif, const float* __restrict__ Whf,
    float* __restrict__ WT) {            // 4 contiguous [128][384] tables
    const int mat = blockIdx.x / 48, tile = blockIdx.x % 48;
    const int tr = tile / 4, tc = tile % 4;      // row-tile (cc), col-tile (k)
    const float* __restrict__ src = (mat == 0) ? Wib : (mat == 1) ? Whb
                                   : (mat == 2) ? Wif : Whf;
    float* __restrict__ dst = WT + (size_t)mat * DD * C3;
    __shared__ float tl[32][33];
    const int tx = threadIdx.x & 31, ty = threadIdx.x >> 5;   // 8 rows/pass
#pragma unroll
    for (int p = 0; p < 32; p += 8) {
        const int cc = tr * 32 + ty + p, k = tc * 32 + tx;
        const float sc = (cc >= 256) ? 2.0f * NL2E : NL2E;
        tl[ty + p][tx] = src[(size_t)cc * DD + k] * sc;
    }
    __syncthreads();
#pragma unroll
    for (int p = 0; p < 32; p += 8) {
        const int k = tc * 32 + ty + p, cc = tr * 32 + tx;
        dst[(size_t)k * C3 + cc] = tl[tx][ty + p];
    }
}

// Pre-scaled packed gate tables, bf16x4 per (row, d):
//   GiP[row][d] = {-L*ir, -L*iz, -2L*in, 0}
//   GhP[row][d] = {-L*hr, -L*hz, -2L*hn, h}
// Block = 4 rows; 256 threads = (half: 0=Gi table, 1=Gh table) x (d 0..127).
// Each thread: 3 gate dots x 4 rows over transposed weights (coalesced).
__global__ __launch_bounds__(256, 4) void gtab_kernel(
    const float* __restrict__ h,
    const float* __restrict__ WiT, const float* __restrict__ WhT,
    const float* __restrict__ bi, const float* __restrict__ bh,
    unsigned short* __restrict__ GiP, unsigned short* __restrict__ GhP) {
    __shared__ float hs[4][DD];
    const int t = threadIdx.x;
    const int r0 = blockIdx.x * 4;
    for (int idx = t; idx < 4 * DD; idx += 256) {
        const int r = idx >> 7, k = idx & (DD - 1);
        hs[r][k] = (r0 + r < ROWS) ? h[(size_t)(r0 + r) * DD + k] : 0.0f;
    }
    __syncthreads();

    const int half = t >> 7, d = t & (DD - 1);
    const float* __restrict__ WT = half ? WhT : WiT;
    const float* __restrict__ bb = half ? bh : bi;
    const float b0 = bb[d] * NL2E;
    const float b1 = bb[DD + d] * NL2E;
    const float b2 = bb[2 * DD + d] * (2.0f * NL2E);
    float a0[4] = {b0, b0, b0, b0};
    float a1[4] = {b1, b1, b1, b1};
    float a2[4] = {b2, b2, b2, b2};
#pragma unroll 4
    for (int k = 0; k < DD; ++k) {
        const float w0 = WT[(size_t)k * C3 + d];
        const float w1 = WT[(size_t)k * C3 + DD + d];
        const float w2 = WT[(size_t)k * C3 + 2 * DD + d];
#pragma unroll
        for (int r = 0; r < 4; ++r) {
            const float hv = hs[r][k];
            a0[r] += hv * w0; a1[r] += hv * w1; a2[r] += hv * w2;
        }
    }
    unsigned short* __restrict__ G = half ? GhP : GiP;
#pragma unroll
    for (int r = 0; r < 4; ++r) {
        if (r0 + r < ROWS) {
            ushort4 o;
            o.x = f2bf(a0[r]); o.y = f2bf(a1[r]); o.z = f2bf(a2[r]);
            o.w = half ? f2bf(hs[r][d]) : (unsigned short)0;
            *reinterpret_cast<ushort4*>(G + (size_t)(r0 + r) * 512 + d * 4) = o;
        }
    }
}

// One block per (b,j); 512 threads = (ic 0..3) x (d 0..127); quarter ic sums 32 i's.
// XC=1: x=child, h=parent (bwd). XC=0: x=parent, h=child (fwd).
template<int XC, int WRITE_OUT>
__global__ __launch_bounds__(512, 4) void phase_kernel(
    const float* __restrict__ hin,
    const int* __restrict__ parent, const int* __restrict__ child,
    const unsigned short* __restrict__ GiP, const unsigned short* __restrict__ GhP,
    float* __restrict__ hout,
    const int* __restrict__ tgt, float* __restrict__ out) {
    const int bj = blockIdx.x;          // 0..1023
    const int t  = threadIdx.x;
    const int b  = bj >> 7, j = bj & (NN - 1);
    const size_t base = (size_t)b * NN * NN + j;          // + i*NN

    __shared__ int   pcs[2 * NN];       // interleaved {p,c} pairs
    __shared__ float sacc[4][DD];
    if (t < NN)            pcs[2 * t]            = parent[base + (size_t)t * NN];
    else if (t < 2 * NN)   pcs[2 * (t - NN) + 1] = child [base + (size_t)(t - NN) * NN];
    __syncthreads();

    const int ic = t >> 7, d = t & (DD - 1);
    float acc = 0.0f;
#pragma unroll 4
    for (int k = 0; k < 32; ++k) {
        const int  i  = ic * 32 + k;
        const int2 pc = *reinterpret_cast<const int2*>(&pcs[2 * i]);
        const int  xi = XC ? pc.y : pc.x;
        const int  hi = XC ? pc.x : pc.y;
        const ushort4 vx = *reinterpret_cast<const ushort4*>(GiP + (size_t)xi * 512 + d * 4);
        const ushort4 vh = *reinterpret_cast<const ushort4*>(GhP + (size_t)hi * 512 + d * 4);
        const float irs = bf2f(vx.x), izs = bf2f(vx.y), ins = bf2f(vx.z);
        const float hrs = bf2f(vh.x), hzs = bf2f(vh.y), hns = bf2f(vh.z), hv = bf2f(vh.w);
        const float r = __builtin_amdgcn_rcpf(1.0f + __builtin_amdgcn_exp2f(irs + hrs));
        const float z = __builtin_amdgcn_rcpf(1.0f + __builtin_amdgcn_exp2f(izs + hzs));
        const float q = __builtin_amdgcn_rcpf(1.0f + __builtin_amdgcn_exp2f(ins + r * hns));
        const float n = 2.0f * q - 1.0f;
        acc += n + z * (hv - n);
    }
    sacc[ic][d] = acc;
    __syncthreads();

    if (ic == 0) {
        const float v   = sacc[0][d] + sacc[1][d] + sacc[2][d] + sacc[3][d];
        const int   row = 1 + bj;
        const float res = hin[(size_t)row * DD + d] + v;
        if (WRITE_OUT) {
#pragma unroll
            for (int bb = 0; bb < BB; ++bb)
                if (tgt[bb] == row) out[bb * DD + d] = res;
        } else {
            hout[(size_t)row * DD + d] = res;
        }
    } else if (ic == 1 && bj == 0 && !WRITE_OUT) {
        hout[d] = hin[d];                 // row 0 unchanged (tgt >= 1 always)
    }
}

extern "C" void kernel_launch(void* const* d_in, const int* in_sizes, int n_in,
                              void* d_out, int out_size, void* d_ws, size_t ws_size,
                              hipStream_t stream) {
    const float* hidden = (const float*)d_in[0];
    const int*   parent = (const int*)d_in[1];
    const int*   child  = (const int*)d_in[2];
    const int*   tgt    = (const int*)d_in[3];
    const float* Wif    = (const float*)d_in[4];
    const float* Whf    = (const float*)d_in[5];
    const float* bif    = (const float*)d_in[6];
    const float* bhf    = (const float*)d_in[7];
    const float* Wib    = (const float*)d_in[8];
    const float* Whb    = (const float*)d_in[9];
    const float* bib    = (const float*)d_in[10];
    const float* bhb    = (const float*)d_in[11];

    char* ws = (char*)d_ws;
    float*          WT  = (float*)(ws);                    // 4 x 128x384 f32 = 786432 B
    unsigned short* GiP = (unsigned short*)(ws + 786432);  // 1025*512 bf16 = 1049600 B
    unsigned short* GhP = (unsigned short*)(ws + 1836032); // 1025*512 bf16
    float*          h1  = (float*)(ws + 2885632);          // 1025*128 f32
    float*          out = (float*)d_out;

    const float* WibT = WT;
    const float* WhbT = WT + DD * C3;
    const float* WifT = WT + 2 * DD * C3;
    const float* WhfT = WT + 3 * DD * C3;

    wprep_kernel<<<192, 256, 0, stream>>>(Wib, Whb, Wif, Whf, WT);
    // Phase 1: bwd weights, x = child, h = parent
    gtab_kernel<<<257, 256, 0, stream>>>(hidden, WibT, WhbT, bib, bhb, GiP, GhP);
    phase_kernel<1, 0><<<BB * NN, 512, 0, stream>>>(hidden, parent, child, GiP, GhP, h1, nullptr, nullptr);
    // Phase 2: fwd weights, x = parent, h = child; tgt gather fused
    gtab_kernel<<<257, 256, 0, stream>>>(h1, WifT, WhfT, bif, bhf, GiP, GhP);
    phase_kernel<0, 1><<<BB * NN, 512, 0, stream>>>(h1, parent, child, GiP, GhP, nullptr, tgt, out);
}